// Round 1
// baseline (2350.260 us; speedup 1.0000x reference)
//
#include <hip/hip_runtime.h>
#include <hip/hip_bf16.h>
#include <math.h>

// MOE transformer block, fp32 baseline.
// B=2, S=2048, DIM=1024, HEADS=16, Dh=64, EXPERTS=8, DFF=4096.
// Pipeline: LN1 -> Q/K/V GEMM -> flash attn -> O-proj GEMM (+resid) -> LN2
//           -> grouped FFN1 (silu) -> grouped FFN2 (+resid) -> d_out.

#define TOKS 4096      // B*S
#define DIM_ 1024
#define DFF_ 4096
#define SEQ 2048
#define EPS_ 1e-5f

// ---------------------------------------------------------------- LayerNorm
__global__ __launch_bounds__(256) void ln_kernel(const float* __restrict__ x,
                                                 const float* __restrict__ g,
                                                 const float* __restrict__ b,
                                                 float* __restrict__ out) {
    int row = blockIdx.x;
    int t = threadIdx.x;                       // 256 threads, 1 float4 each (1024 cols)
    const float4* xr = (const float4*)(x + (size_t)row * DIM_);
    float4 v = xr[t];
    float s  = v.x + v.y + v.z + v.w;
    float ss = v.x*v.x + v.y*v.y + v.z*v.z + v.w*v.w;
    #pragma unroll
    for (int off = 32; off > 0; off >>= 1) {
        s  += __shfl_down(s, off);
        ss += __shfl_down(ss, off);
    }
    __shared__ float red[8];
    if ((t & 63) == 0) { red[t >> 6] = s; red[4 + (t >> 6)] = ss; }
    __syncthreads();
    s  = red[0] + red[1] + red[2] + red[3];
    ss = red[4] + red[5] + red[6] + red[7];
    float mean = s * (1.0f / DIM_);
    float var  = ss * (1.0f / DIM_) - mean * mean;
    float rstd = rsqrtf(var + EPS_);
    float4 gv = ((const float4*)g)[t];
    float4 bv = ((const float4*)b)[t];
    float4 ov;
    ov.x = (v.x - mean) * rstd * gv.x + bv.x;
    ov.y = (v.y - mean) * rstd * gv.y + bv.y;
    ov.z = (v.z - mean) * rstd * gv.z + bv.z;
    ov.w = (v.w - mean) * rstd * gv.w + bv.w;
    ((float4*)(out + (size_t)row * DIM_))[t] = ov;
}

// ---------------------------------------------------------------- fp32 GEMM
// C[M,N] = A[M,K] @ W[K,N] + bias[N] (+resid) (ACT==1: silu)
// GROUPED: blockIdx.y encodes (batch,expert,half): per-expert weights/bias,
// rows b*2048 + e*256 + half*128. M is always a multiple of 128, N of 128,
// K of 16 -> no guards.
template<int ACT, bool GROUPED>
__global__ __launch_bounds__(256) void gemm_kernel(const float* __restrict__ A,
                                                   const float* __restrict__ W,
                                                   const float* __restrict__ bias,
                                                   const float* __restrict__ resid,
                                                   float* __restrict__ C,
                                                   int N, int K) {
    constexpr int BM = 128, BN = 128, BK = 16, TM = 8, TN = 8;
    __shared__ float As[BK][BM + 4];   // transposed store, pad keeps 16B align
    __shared__ float Bs[BK][BN + 4];

    int tid = threadIdx.x;
    int tx = tid & 15, ty = tid >> 4;

    long row0;
    if (GROUPED) {
        int seg = blockIdx.y >> 1;          // 0..15
        int mh  = blockIdx.y & 1;
        int bb  = seg >> 3, e = seg & 7;
        row0 = (long)bb * SEQ + (long)e * 256 + (long)mh * BM;
        W    += (size_t)e * K * N;
        bias += (size_t)e * N;
    } else {
        row0 = (long)blockIdx.y * BM;
    }
    int col0 = blockIdx.x * BN;
    A += row0 * K;
    C += row0 * (long)N;
    if (resid) resid += row0 * (long)N;

    float acc[TM][TN];
    #pragma unroll
    for (int m = 0; m < TM; m++)
        #pragma unroll
        for (int n = 0; n < TN; n++) acc[m][n] = 0.0f;

    for (int kt = 0; kt < K; kt += BK) {
        // A tile 128x16 -> transposed into As
        #pragma unroll
        for (int i = 0; i < 2; i++) {
            int f = tid + i * 256;
            int r = f >> 2, c = (f & 3) << 2;
            float4 av = *(const float4*)&A[(long)r * K + kt + c];
            As[c + 0][r] = av.x; As[c + 1][r] = av.y;
            As[c + 2][r] = av.z; As[c + 3][r] = av.w;
        }
        // B tile 16x128 natural
        #pragma unroll
        for (int i = 0; i < 2; i++) {
            int f = tid + i * 256;
            int r = f >> 5, c = (f & 31) << 2;
            *(float4*)&Bs[r][c] = *(const float4*)&W[(long)(kt + r) * N + col0 + c];
        }
        __syncthreads();
        #pragma unroll
        for (int kk = 0; kk < BK; kk++) {
            float a[TM], bb2[TN];
            *(float4*)&a[0]   = *(const float4*)&As[kk][ty * TM];
            *(float4*)&a[4]   = *(const float4*)&As[kk][ty * TM + 4];
            *(float4*)&bb2[0] = *(const float4*)&Bs[kk][tx * TN];
            *(float4*)&bb2[4] = *(const float4*)&Bs[kk][tx * TN + 4];
            #pragma unroll
            for (int m = 0; m < TM; m++)
                #pragma unroll
                for (int n = 0; n < TN; n++)
                    acc[m][n] = fmaf(a[m], bb2[n], acc[m][n]);
        }
        __syncthreads();
    }
    // epilogue
    #pragma unroll
    for (int m = 0; m < TM; m++) {
        long r = ty * TM + m;
        #pragma unroll
        for (int n4 = 0; n4 < 2; n4++) {
            int cc = col0 + tx * TN + n4 * 4;
            float4 bv = *(const float4*)&bias[cc];
            float4 val;
            val.x = acc[m][n4 * 4 + 0] + bv.x;
            val.y = acc[m][n4 * 4 + 1] + bv.y;
            val.z = acc[m][n4 * 4 + 2] + bv.z;
            val.w = acc[m][n4 * 4 + 3] + bv.w;
            if (ACT == 1) {   // silu
                val.x = val.x / (1.0f + __expf(-val.x));
                val.y = val.y / (1.0f + __expf(-val.y));
                val.z = val.z / (1.0f + __expf(-val.z));
                val.w = val.w / (1.0f + __expf(-val.w));
            }
            if (resid) {
                float4 rv = *(const float4*)&resid[r * N + cc];
                val.x += rv.x; val.y += rv.y; val.z += rv.z; val.w += rv.w;
            }
            *(float4*)&C[r * N + cc] = val;
        }
    }
}

// ---------------------------------------------------------------- attention
// Flash-style fp32. Block = (q-tile of 64 rows, head, batch). Non-causal,
// S=2048, Dh=64. q/k/v layout: [(b*S+s)*1024 + h*64 + d].
__global__ __launch_bounds__(256) void attn_kernel(const float* __restrict__ q,
                                                   const float* __restrict__ k,
                                                   const float* __restrict__ v,
                                                   float* __restrict__ o) {
    int qt = blockIdx.x;       // 0..31
    int h  = blockIdx.y;       // 0..15
    int b  = blockIdx.z;       // 0..1
    int tid = threadIdx.x;
    int tx = tid & 15, ty = tid >> 4;

    __shared__ float Qt[64][68];   // [d][qr]  (transposed)
    __shared__ float Kt[64][68];   // [d][kr]  (transposed)
    __shared__ float Vs[64][68];   // [kr][d]  (natural)
    __shared__ float Pt[64][68];   // [kr][qr] (transposed probs)

    const size_t base = (size_t)b * SEQ * DIM_ + (size_t)h * 64;
    int q0 = qt * 64;

    // load Q tile transposed
    #pragma unroll
    for (int i = 0; i < 4; i++) {
        int f = tid + i * 256;
        int r = f >> 4, c = (f & 15) << 2;
        float4 vv = *(const float4*)&q[base + (size_t)(q0 + r) * DIM_ + c];
        Qt[c + 0][r] = vv.x; Qt[c + 1][r] = vv.y;
        Qt[c + 2][r] = vv.z; Qt[c + 3][r] = vv.w;
    }

    float m_i[4], l_i[4], oacc[4][4];
    #pragma unroll
    for (int i = 0; i < 4; i++) {
        m_i[i] = -1e30f; l_i[i] = 0.0f;
        #pragma unroll
        for (int j = 0; j < 4; j++) oacc[i][j] = 0.0f;
    }

    for (int kt_ = 0; kt_ < SEQ / 64; kt_++) {
        __syncthreads();   // previous PV done before overwriting Kt/Vs
        #pragma unroll
        for (int i = 0; i < 4; i++) {
            int f = tid + i * 256;
            int r = f >> 4, c = (f & 15) << 2;
            size_t gidx = base + (size_t)(kt_ * 64 + r) * DIM_ + c;
            float4 kv = *(const float4*)&k[gidx];
            Kt[c + 0][r] = kv.x; Kt[c + 1][r] = kv.y;
            Kt[c + 2][r] = kv.z; Kt[c + 3][r] = kv.w;
            *(float4*)&Vs[r][c] = *(const float4*)&v[gidx];
        }
        __syncthreads();

        // scores s[4][4]: rows q0+ty*4+i, cols kt_*64+tx*4+j
        float s[4][4];
        #pragma unroll
        for (int i = 0; i < 4; i++)
            #pragma unroll
            for (int j = 0; j < 4; j++) s[i][j] = 0.0f;
        #pragma unroll 8
        for (int d = 0; d < 64; d++) {
            float4 qa = *(const float4*)&Qt[d][ty * 4];
            float4 ka = *(const float4*)&Kt[d][tx * 4];
            float qa_[4] = {qa.x, qa.y, qa.z, qa.w};
            float ka_[4] = {ka.x, ka.y, ka.z, ka.w};
            #pragma unroll
            for (int i = 0; i < 4; i++)
                #pragma unroll
                for (int j = 0; j < 4; j++)
                    s[i][j] = fmaf(qa_[i], ka_[j], s[i][j]);
        }

        // online softmax update
        float p[4][4], corr[4];
        #pragma unroll
        for (int i = 0; i < 4; i++) {
            float rmax = fmaxf(fmaxf(s[i][0], s[i][1]), fmaxf(s[i][2], s[i][3])) * 0.125f;
            #pragma unroll
            for (int off = 1; off < 16; off <<= 1)
                rmax = fmaxf(rmax, __shfl_xor(rmax, off));
            float mnew = fmaxf(m_i[i], rmax);
            corr[i] = __expf(m_i[i] - mnew);
            m_i[i] = mnew;
            float rsum = 0.0f;
            #pragma unroll
            for (int j = 0; j < 4; j++) {
                p[i][j] = __expf(s[i][j] * 0.125f - mnew);
                rsum += p[i][j];
            }
            #pragma unroll
            for (int off = 1; off < 16; off <<= 1)
                rsum += __shfl_xor(rsum, off);
            l_i[i] = l_i[i] * corr[i] + rsum;
            #pragma unroll
            for (int j = 0; j < 4; j++) oacc[i][j] *= corr[i];
        }
        // stash probs transposed
        #pragma unroll
        for (int i = 0; i < 4; i++)
            #pragma unroll
            for (int j = 0; j < 4; j++)
                Pt[tx * 4 + j][ty * 4 + i] = p[i][j];
        __syncthreads();

        // PV: oacc[i][j] += sum_kc Pt[kc][ty*4+i] * Vs[kc][tx*4+j]
        #pragma unroll 8
        for (int kc = 0; kc < 64; kc++) {
            float4 pa = *(const float4*)&Pt[kc][ty * 4];
            float4 va = *(const float4*)&Vs[kc][tx * 4];
            float pa_[4] = {pa.x, pa.y, pa.z, pa.w};
            float va_[4] = {va.x, va.y, va.z, va.w};
            #pragma unroll
            for (int i = 0; i < 4; i++)
                #pragma unroll
                for (int j = 0; j < 4; j++)
                    oacc[i][j] = fmaf(pa_[i], va_[j], oacc[i][j]);
        }
    }

    // write O
    #pragma unroll
    for (int i = 0; i < 4; i++) {
        float inv = 1.0f / l_i[i];
        float4 ov;
        ov.x = oacc[i][0] * inv; ov.y = oacc[i][1] * inv;
        ov.z = oacc[i][2] * inv; ov.w = oacc[i][3] * inv;
        *(float4*)&o[base + (size_t)(q0 + ty * 4 + i) * DIM_ + tx * 4] = ov;
    }
}

// ---------------------------------------------------------------- launcher
extern "C" void kernel_launch(void* const* d_in, const int* in_sizes, int n_in,
                              void* d_out, int out_size, void* d_ws, size_t ws_size,
                              hipStream_t stream) {
    const float* x     = (const float*)d_in[0];
    const float* ln1_g = (const float*)d_in[1];
    const float* ln1_b = (const float*)d_in[2];
    const float* ln2_g = (const float*)d_in[3];
    const float* ln2_b = (const float*)d_in[4];
    const float* wq = (const float*)d_in[5];  const float* bq = (const float*)d_in[6];
    const float* wk = (const float*)d_in[7];  const float* bk = (const float*)d_in[8];
    const float* wv = (const float*)d_in[9];  const float* bv = (const float*)d_in[10];
    const float* wo = (const float*)d_in[11]; const float* bo = (const float*)d_in[12];
    const float* w1 = (const float*)d_in[13]; const float* b1 = (const float*)d_in[14];
    const float* w2 = (const float*)d_in[15]; const float* b2 = (const float*)d_in[16];

    float* ws = (float*)d_ws;
    const size_t SZ = (size_t)TOKS * DIM_;       // 4M floats
    float* h1  = ws;                              // LN1 out
    float* qb  = ws + 1 * SZ;
    float* kb  = ws + 2 * SZ;
    float* vb  = ws + 3 * SZ;
    float* x2  = ws + 4 * SZ;                     // attn residual out
    float* mid = ws + 5 * SZ;                     // FFN mid, 16M floats
    float* ob  = h1;                              // reuse: attn out
    float* h2  = qb;                              // reuse: LN2 out
    float* outp = (float*)d_out;

    dim3 blk(256);
    ln_kernel<<<TOKS, blk, 0, stream>>>(x, ln1_g, ln1_b, h1);

    gemm_kernel<0, false><<<dim3(8, 32), blk, 0, stream>>>(h1, wq, bq, nullptr, qb, DIM_, DIM_);
    gemm_kernel<0, false><<<dim3(8, 32), blk, 0, stream>>>(h1, wk, bk, nullptr, kb, DIM_, DIM_);
    gemm_kernel<0, false><<<dim3(8, 32), blk, 0, stream>>>(h1, wv, bv, nullptr, vb, DIM_, DIM_);

    attn_kernel<<<dim3(32, 16, 2), blk, 0, stream>>>(qb, kb, vb, ob);

    gemm_kernel<0, false><<<dim3(8, 32), blk, 0, stream>>>(ob, wo, bo, x, x2, DIM_, DIM_);

    ln_kernel<<<TOKS, blk, 0, stream>>>(x2, ln2_g, ln2_b, h2);

    gemm_kernel<1, true><<<dim3(32, 32), blk, 0, stream>>>(h2, w1, b1, nullptr, mid, DFF_, DIM_);
    gemm_kernel<0, true><<<dim3(8, 32), blk, 0, stream>>>(mid, w2, b2, x2, outp, DIM_, DFF_);
}

// Round 3
// 589.487 us; speedup vs baseline: 3.9870x; 3.9870x over previous
//
#include <hip/hip_runtime.h>

// MOE transformer block — bf16 MFMA version.
// B=2, S=2048, DIM=1024, HEADS=16, Dh=64, EXPERTS=8, DFF=4096.
// LN1->QKV gemm (V written transposed)->flash attn (MFMA)->O-proj(+resid)
// ->LN2->grouped FFN1(silu)->grouped FFN2(+resid)->d_out.
// All matmuls: v_mfma_f32_16x16x32_bf16, fp32 accum. Residuals/LN/softmax fp32.

typedef unsigned int  u32;
typedef unsigned short u16;
typedef short v8s __attribute__((ext_vector_type(8)));   // 8 x bf16 fragment
typedef float v4f __attribute__((ext_vector_type(4)));   // 4 x f32 accum

#define SEQ  2048
#define DIM_ 1024
#define EPS_ 1e-5f

__device__ __forceinline__ u16 f2bf(float f) {
    __bf16 h = (__bf16)f;                 // RNE, compiler handles cvt (m240)
    return __builtin_bit_cast(u16, h);
}

__device__ __forceinline__ void gload16(const void* g, void* l) {
    // async global->LDS, 16B/lane; dst is wave-uniform base + lane*16
    __builtin_amdgcn_global_load_lds((const __attribute__((address_space(1))) u32*)g,
                                     (__attribute__((address_space(3))) u32*)l, 16, 0, 0);
}

// ---------------------------------------------------------------- LayerNorm (fp32 in, bf16 out)
__global__ __launch_bounds__(256) void ln_kernel(const float* __restrict__ x,
                                                 const float* __restrict__ g,
                                                 const float* __restrict__ b,
                                                 u16* __restrict__ out) {
    int row = blockIdx.x;
    int t = threadIdx.x;
    const float4* xr = (const float4*)(x + (size_t)row * DIM_);
    float4 v = xr[t];
    float s  = v.x + v.y + v.z + v.w;
    float ss = v.x*v.x + v.y*v.y + v.z*v.z + v.w*v.w;
    #pragma unroll
    for (int off = 32; off > 0; off >>= 1) {
        s  += __shfl_down(s, off);
        ss += __shfl_down(ss, off);
    }
    __shared__ float red[8];
    if ((t & 63) == 0) { red[t >> 6] = s; red[4 + (t >> 6)] = ss; }
    __syncthreads();
    s  = red[0] + red[1] + red[2] + red[3];
    ss = red[4] + red[5] + red[6] + red[7];
    float mean = s * (1.0f / DIM_);
    float var  = ss * (1.0f / DIM_) - mean * mean;
    float rstd = rsqrtf(var + EPS_);
    float4 gv = ((const float4*)g)[t];
    float4 bv = ((const float4*)b)[t];
    ushort4 ov;
    ov.x = f2bf((v.x - mean) * rstd * gv.x + bv.x);
    ov.y = f2bf((v.y - mean) * rstd * gv.y + bv.y);
    ov.z = f2bf((v.z - mean) * rstd * gv.z + bv.z);
    ov.w = f2bf((v.w - mean) * rstd * gv.w + bv.w);
    *(ushort4*)(out + (size_t)row * DIM_ + t * 4) = ov;
}

// ---------------------------------------------------------------- bf16 MFMA GEMM
// C[M,N] = A[M,K](bf16) @ W[K,N](fp32, cast in staging) + bias
// WMODE 0: fp32 out + resid ; 1: bf16 out (ACT=silu opt) ; 2: fused QKV (q,k natural bf16; v -> V^T)
// GROUPED: blockIdx.y = seg*2+mh, seg=(batch,expert): rows bb*2048+e*256+mh*128,
//          per-expert W/bias.
template<int BN, int ACT, bool GROUPED, int WMODE>
__global__ __launch_bounds__(256) void gemm_bf16(
    const u16* __restrict__ A,
    const float* __restrict__ W0, const float* __restrict__ Wk, const float* __restrict__ Wv,
    const float* __restrict__ b0, const float* __restrict__ bk2, const float* __restrict__ bv2,
    const float* __restrict__ resid, float* __restrict__ Cf,
    u16* __restrict__ Cb, u16* __restrict__ Ckb, u16* __restrict__ vtb,
    int Nw, int K)
{
    constexpr int BM = 128;
    constexpr int MI = 4;
    constexpr int NI = BN / 32;           // frags per wave in N (4 or 2)
    constexpr int SL = BN / 32;           // B-staging slot-groups per thread (4 or 2)
    __shared__ __attribute__((aligned(16))) char AsB[BM * 128];  // [row][64k] bf16, XOR-swizzled slots
    __shared__ __attribute__((aligned(16))) char BsB[BN * 128];  // [n][64k]  bf16, XOR-swizzled slots

    int tid = threadIdx.x;
    int lane = tid & 63, w = tid >> 6;
    int wr = w >> 1, wc = w & 1;
    int g = lane >> 4, lq = lane & 15;

    long row0; const float* W = W0; const float* bias = b0;
    if (GROUPED) {
        int seg = blockIdx.y >> 1, mh = blockIdx.y & 1;
        int bb = seg >> 3, e = seg & 7;
        row0 = (long)bb * SEQ + e * 256 + mh * BM;
        W += (size_t)e * K * Nw; bias += (size_t)e * Nw;
    } else row0 = (long)blockIdx.y * BM;

    int col0 = blockIdx.x * BN;
    int colL = col0;
    if (WMODE == 2) {
        int sel = col0 >> 10; colL = col0 & 1023;
        if (sel == 1)      { W = Wk; bias = bk2; }
        else if (sel == 2) { W = Wv; bias = bv2; }
    }

    const u16* Arow = A + row0 * K;

    v4f acc[MI][NI];
    #pragma unroll
    for (int mi = 0; mi < MI; mi++)
        #pragma unroll
        for (int ni = 0; ni < NI; ni++) acc[mi][ni] = (v4f){0.f, 0.f, 0.f, 0.f};

    int nB = tid & (BN - 1);
    int sgB = tid / BN;

    for (int kt = 0; kt < K; kt += 64) {
        // ---- A stage: global_load_lds, linear dest, inverse-swizzled SOURCE (rule 21)
        #pragma unroll
        for (int i = 0; i < 4; i++) {
            int row  = (i * 4 + w) * 8 + (lane >> 3);
            int scol = ((lane & 7) ^ (row & 7)) << 3;
            gload16(Arow + (size_t)row * K + kt + scol, AsB + (i * 4 + w) * 1024);
        }
        // ---- B stage: fp32 loads (coalesced along n) -> bf16 -> swizzled ds_write_b128
        #pragma unroll
        for (int i = 0; i < SL; i++) {
            int s = sgB * SL + i;
            float fv[8];
            #pragma unroll
            for (int j = 0; j < 8; j++)
                fv[j] = W[(size_t)(kt + s * 8 + j) * Nw + colL + nB];
            union { v8s v; u16 u[8]; } pk;
            #pragma unroll
            for (int j = 0; j < 8; j++) pk.u[j] = f2bf(fv[j]);
            *(v8s*)(BsB + nB * 128 + ((s ^ (nB & 7)) << 4)) = pk.v;
        }
        __syncthreads();
        // ---- compute: 2 k-steps x MI x NI MFMA
        #pragma unroll
        for (int kk = 0; kk < 64; kk += 32) {
            v8s af[MI], bfv[NI];
            int slot = (kk >> 3) + g;
            #pragma unroll
            for (int mi = 0; mi < MI; mi++) {
                int row = wr * 64 + mi * 16 + lq;
                af[mi] = *(const v8s*)(AsB + row * 128 + ((slot ^ (row & 7)) << 4));
            }
            #pragma unroll
            for (int ni = 0; ni < NI; ni++) {
                int rn = wc * (BN / 2) + ni * 16 + lq;
                bfv[ni] = *(const v8s*)(BsB + rn * 128 + ((slot ^ (rn & 7)) << 4));
            }
            #pragma unroll
            for (int mi = 0; mi < MI; mi++)
                #pragma unroll
                for (int ni = 0; ni < NI; ni++)
                    acc[mi][ni] = __builtin_amdgcn_mfma_f32_16x16x32_bf16(
                        af[mi], bfv[ni], acc[mi][ni], 0, 0, 0);
        }
        __syncthreads();
    }

    // ---- epilogue. D frag: row=(lane>>4)*4+r, col=lane&15
    #pragma unroll
    for (int mi = 0; mi < MI; mi++) {
        int grow = wr * 64 + mi * 16 + g * 4;
        #pragma unroll
        for (int ni = 0; ni < NI; ni++) {
            int cL = colL + wc * (BN / 2) + ni * 16 + lq;
            float bb_ = bias[cL];
            v4f a = acc[mi][ni];
            if (WMODE == 0) {
                #pragma unroll
                for (int r = 0; r < 4; r++) {
                    float val = a[r] + bb_;
                    if (ACT == 1) val = val / (1.0f + __expf(-val));
                    size_t idx = (size_t)(row0 + grow + r) * Nw + cL;
                    val += resid[idx];
                    Cf[idx] = val;
                }
            } else if (WMODE == 1) {
                #pragma unroll
                for (int r = 0; r < 4; r++) {
                    float val = a[r] + bb_;
                    if (ACT == 1) val = val / (1.0f + __expf(-val));
                    Cb[(size_t)(row0 + grow + r) * Nw + cL] = f2bf(val);
                }
            } else {
                int sel = col0 >> 10;
                if (sel < 2) {
                    u16* dst = (sel == 0) ? Cb : Ckb;
                    #pragma unroll
                    for (int r = 0; r < 4; r++)
                        dst[(size_t)(row0 + grow + r) * 1024 + cL] = f2bf(a[r] + bb_);
                } else {
                    long token0 = row0 + grow;
                    int bb2 = (int)(token0 >> 11);
                    int ss  = (int)(token0 & 2047);
                    int hh = cL >> 6, dd = cL & 63;
                    ushort4 pv_;
                    pv_.x = f2bf(a[0] + bb_); pv_.y = f2bf(a[1] + bb_);
                    pv_.z = f2bf(a[2] + bb_); pv_.w = f2bf(a[3] + bb_);
                    *(ushort4*)(vtb + ((size_t)(bb2 * 16 + hh) * 64 + dd) * 2048 + ss) = pv_;
                }
            }
        }
    }
}

// ---------------------------------------------------------------- MFMA flash attention
// grid (16 qtiles, 16 heads, 2 batch), 256 thr = 4 waves, 32 q-rows/wave.
// Swapped QK^T: D[key][q] so softmax stats are 2 shfl_xor per row-group (T12 idea).
// Defer-max rescale (T13, THR=8). P via per-wave padded LDS. fp32 softmax/accum.
__global__ __launch_bounds__(256) void attn_kernel(const u16* __restrict__ qb,
                                                   const u16* __restrict__ kb,
                                                   const u16* __restrict__ vtb,
                                                   u16* __restrict__ ob) {
    __shared__ __attribute__((aligned(16))) char Kl[8192];   // [key 0..63][d 0..63] bf16, swizzled
    __shared__ __attribute__((aligned(16))) char Vl[8192];   // [d 0..63][key 0..63] bf16 (V^T), swizzled
    __shared__ __attribute__((aligned(16))) char Pl[4][4608];// per-wave [32 q][72] bf16 (row 144B)

    int tid = threadIdx.x;
    int lane = tid & 63, w = tid >> 6;
    int g = lane >> 4, lq = lane & 15;
    int h = blockIdx.y, bz = blockIdx.z;
    int q0 = blockIdx.x * 128 + w * 32;
    const size_t hb = (size_t)h * 64;

    // hoist Q fragments (B-operand of swapped QK^T): q = qf*16+lq, d = kk + g*8..
    v8s qfr[2][2];
    #pragma unroll
    for (int qi = 0; qi < 2; qi++)
        #pragma unroll
        for (int kkh = 0; kkh < 2; kkh++)
            qfr[qi][kkh] = *(const v8s*)(qb + ((size_t)(bz * SEQ + q0 + qi * 16 + lq)) * DIM_
                                         + hb + kkh * 32 + g * 8);

    v4f oacc[2][4];
    #pragma unroll
    for (int qi = 0; qi < 2; qi++)
        #pragma unroll
        for (int df = 0; df < 4; df++) oacc[qi][df] = (v4f){0.f, 0.f, 0.f, 0.f};
    float m_prev[2] = {-1e30f, -1e30f}, l_acc[2] = {0.f, 0.f};

    for (int kv = 0; kv < SEQ; kv += 64) {
        __syncthreads();                                   // prev PV done
        #pragma unroll
        for (int i = 0; i < 2; i++) {
            int beta = (i * 4 + w) * 1024 + lane * 16;
            int row  = beta >> 7;
            int sc   = ((lane & 7) ^ (row & 7)) << 3;
            gload16(kb + ((size_t)(bz * SEQ + kv + row)) * DIM_ + hb + sc,
                    Kl + (i * 4 + w) * 1024);
            gload16(vtb + ((size_t)((bz * 16 + h) * 64 + row)) * 2048 + kv + sc,
                    Vl + (i * 4 + w) * 1024);
        }
        __syncthreads();                                   // stage complete (drains vmcnt)

        // QK^T swapped: sa[cf][qi], D rows = keys cf*16+g*4+r, col q = qi*16+lq
        v4f sa[4][2];
        #pragma unroll
        for (int cf = 0; cf < 4; cf++)
            #pragma unroll
            for (int qi = 0; qi < 2; qi++) sa[cf][qi] = (v4f){0.f, 0.f, 0.f, 0.f};
        #pragma unroll
        for (int kkh = 0; kkh < 2; kkh++) {
            v8s kf[4];
            int slot = kkh * 4 + g;
            #pragma unroll
            for (int cf = 0; cf < 4; cf++) {
                int row = cf * 16 + lq;
                kf[cf] = *(const v8s*)(Kl + row * 128 + ((slot ^ (row & 7)) << 4));
            }
            #pragma unroll
            for (int cf = 0; cf < 4; cf++)
                #pragma unroll
                for (int qi = 0; qi < 2; qi++)
                    sa[cf][qi] = __builtin_amdgcn_mfma_f32_16x16x32_bf16(
                        kf[cf], qfr[qi][kkh], sa[cf][qi], 0, 0, 0);
        }

        // online softmax per qi; lane owns stats of q-row (qi*16+lq)
        #pragma unroll
        for (int qi = 0; qi < 2; qi++) {
            float mx = -1e30f;
            #pragma unroll
            for (int cf = 0; cf < 4; cf++)
                #pragma unroll
                for (int r = 0; r < 4; r++) mx = fmaxf(mx, sa[cf][qi][r]);
            mx = fmaxf(mx, __shfl_xor(mx, 16));
            mx = fmaxf(mx, __shfl_xor(mx, 32));
            float rm = mx * 0.125f;
            if (__any(rm - m_prev[qi] > 8.0f)) {           // defer-max (T13)
                float mnew = fmaxf(m_prev[qi], rm);
                float corr = __expf(m_prev[qi] - mnew);
                m_prev[qi] = mnew;
                l_acc[qi] *= corr;
                #pragma unroll
                for (int r = 0; r < 4; r++) {
                    float cr = __shfl(corr, (lane & 48) | (g * 4 + r));
                    #pragma unroll
                    for (int df = 0; df < 4; df++) oacc[qi][df][r] *= cr;
                }
            }
            float rs = 0.f;
            float ps[4][4];
            #pragma unroll
            for (int cf = 0; cf < 4; cf++)
                #pragma unroll
                for (int r = 0; r < 4; r++) {
                    float p = __expf(sa[cf][qi][r] * 0.125f - m_prev[qi]);
                    ps[cf][r] = p; rs += p;
                }
            rs += __shfl_xor(rs, 16);
            rs += __shfl_xor(rs, 32);
            l_acc[qi] += rs;
            #pragma unroll
            for (int cf = 0; cf < 4; cf++) {
                ushort4 pw;
                pw.x = f2bf(ps[cf][0]); pw.y = f2bf(ps[cf][1]);
                pw.z = f2bf(ps[cf][2]); pw.w = f2bf(ps[cf][3]);
                *(ushort4*)(Pl[w] + (qi * 16 + lq) * 144 + (cf * 16 + g * 4) * 2) = pw;
            }
        }
        asm volatile("s_waitcnt lgkmcnt(0)" ::: "memory"); // P write->read, same wave
        __builtin_amdgcn_sched_barrier(0);                 // rule 18

        // PV: A = P[q][key] from Pl, B = V^T-frag from Vl; D[q][d]
        #pragma unroll
        for (int kkh = 0; kkh < 2; kkh++) {
            v8s pa[2], vf[4];
            int slot = kkh * 4 + g;
            #pragma unroll
            for (int qi = 0; qi < 2; qi++)
                pa[qi] = *(const v8s*)(Pl[w] + (qi * 16 + lq) * 144 + kkh * 64 + g * 16);
            #pragma unroll
            for (int df = 0; df < 4; df++) {
                int row = df * 16 + lq;
                vf[df] = *(const v8s*)(Vl + row * 128 + ((slot ^ (row & 7)) << 4));
            }
            #pragma unroll
            for (int qi = 0; qi < 2; qi++)
                #pragma unroll
                for (int df = 0; df < 4; df++)
                    oacc[qi][df] = __builtin_amdgcn_mfma_f32_16x16x32_bf16(
                        pa[qi], vf[df], oacc[qi][df], 0, 0, 0);
        }
    }

    // epilogue: O[q][d] * (1/l), bf16 natural
    #pragma unroll
    for (int qi = 0; qi < 2; qi++) {
        float inv = 1.0f / l_acc[qi];
        #pragma unroll
        for (int r = 0; r < 4; r++) {
            float ivr = __shfl(inv, (lane & 48) | (g * 4 + r));
            size_t rowi = (size_t)(bz * SEQ + q0 + qi * 16 + g * 4 + r) * DIM_ + hb;
            #pragma unroll
            for (int df = 0; df < 4; df++)
                ob[rowi + df * 16 + lq] = f2bf(oacc[qi][df][r] * ivr);
        }
    }
}

// ---------------------------------------------------------------- launcher
extern "C" void kernel_launch(void* const* d_in, const int* in_sizes, int n_in,
                              void* d_out, int out_size, void* d_ws, size_t ws_size,
                              hipStream_t stream) {
    const float* x     = (const float*)d_in[0];
    const float* ln1_g = (const float*)d_in[1];
    const float* ln1_b = (const float*)d_in[2];
    const float* ln2_g = (const float*)d_in[3];
    const float* ln2_b = (const float*)d_in[4];
    const float* wq = (const float*)d_in[5];  const float* bq = (const float*)d_in[6];
    const float* wk = (const float*)d_in[7];  const float* bk = (const float*)d_in[8];
    const float* wv = (const float*)d_in[9];  const float* bv = (const float*)d_in[10];
    const float* wo = (const float*)d_in[11]; const float* bo = (const float*)d_in[12];
    const float* w1 = (const float*)d_in[13]; const float* b1 = (const float*)d_in[14];
    const float* w2 = (const float*)d_in[15]; const float* b2 = (const float*)d_in[16];

    char* wsb = (char*)d_ws;
    const size_t MB = 1024 * 1024;
    u16*   h1  = (u16*)(wsb + 0 * MB);     // 8 MB  bf16 [4096][1024]
    u16*   qbf = (u16*)(wsb + 8 * MB);     // 8 MB
    u16*   kbf = (u16*)(wsb + 16 * MB);    // 8 MB
    u16*   vt  = (u16*)(wsb + 24 * MB);    // 8 MB  V^T [2][16][64][2048]
    float* x2  = (float*)(wsb + 32 * MB);  // 16 MB fp32
    u16*   mid = (u16*)(wsb + 48 * MB);    // 32 MB bf16 [4096][4096]
    u16*   ob  = h1;                       // reuse (h1 dead after QKV gemm)
    u16*   h2  = qbf;                      // reuse (q dead after attn)
    float* outp = (float*)d_out;

    ln_kernel<<<4096, 256, 0, stream>>>(x, ln1_g, ln1_b, h1);

    // fused QKV: logical N = 3072 (each 128-col block within one of q/k/v)
    gemm_bf16<128, 0, false, 2><<<dim3(24, 32), 256, 0, stream>>>(
        h1, wq, wk, wv, bq, bk, bv, nullptr, nullptr, qbf, kbf, vt, 1024, 1024);

    attn_kernel<<<dim3(16, 16, 2), 256, 0, stream>>>(qbf, kbf, vt, ob);

    gemm_bf16<64, 0, false, 0><<<dim3(16, 32), 256, 0, stream>>>(
        ob, wo, nullptr, nullptr, bo, nullptr, nullptr, x, x2,
        nullptr, nullptr, nullptr, 1024, 1024);

    ln_kernel<<<4096, 256, 0, stream>>>(x2, ln2_g, ln2_b, h2);

    gemm_bf16<128, 1, true, 1><<<dim3(32, 32), 256, 0, stream>>>(
        h2, w1, nullptr, nullptr, b1, nullptr, nullptr, nullptr, nullptr,
        mid, nullptr, nullptr, 4096, 1024);

    gemm_bf16<64, 0, true, 0><<<dim3(16, 32), 256, 0, stream>>>(
        mid, w2, nullptr, nullptr, b2, nullptr, nullptr, x2, outp,
        nullptr, nullptr, nullptr, 1024, 4096);
}